// Round 6
// baseline (993.844 us; speedup 1.0000x reference)
//
#include <hip/hip_runtime.h>
#include <hip/hip_fp16.h>

// BN scale constant: 1/sqrt(1+1e-5)
#define RSQ_BN 0.9999950000374997f

__device__ __forceinline__ float leaky02(float x) { return x > 0.f ? x : 0.2f * x; }

__device__ __forceinline__ float4 ld4(const float* p) {
    return *reinterpret_cast<const float4*>(p);
}
__device__ __forceinline__ void st4(float* p, float4 v) {
    *reinterpret_cast<float4*>(p) = v;
}
__device__ __forceinline__ void sth4(__half* p, float4 v) {
    union { uint2 u; __half2 h[2]; } pk;
    pk.h[0] = __floats2half2_rn(v.x, v.y);
    pk.h[1] = __floats2half2_rn(v.z, v.w);
    *reinterpret_cast<uint2*>(p) = pk.u;
}
__device__ __forceinline__ float4 h4f(uint2 u) {
    union { uint2 u; __half2 h[2]; } pk;
    pk.u = u;
    float2 lo = __half22float2(pk.h[0]);
    float2 hi = __half22float2(pk.h[1]);
    return make_float4(lo.x, lo.y, hi.x, hi.y);
}
__device__ __forceinline__ float4 f4z() { return make_float4(0.f, 0.f, 0.f, 0.f); }

// ---------------- CSR build ----------------

__global__ void zero_i32_k(int* __restrict__ p, int n) {
    int i = blockIdx.x * 256 + threadIdx.x;
    if (i < n) p[i] = 0;
}

__global__ void hist_k(const int* __restrict__ edst, int* __restrict__ cnt, int E, int EN) {
    int i = blockIdx.x * 256 + threadIdx.x;
    if (i >= EN) return;
    int d = (i < E) ? edst[i] : (i - E);   // self-loop for i>=E
    atomicAdd(&cnt[d], 1);
}

__global__ __launch_bounds__(256)
void scanA_k(const int* __restrict__ cnt, int* __restrict__ rowptr,
             int* __restrict__ bsum, int n) {
    __shared__ int sh[256];
    int t = threadIdx.x;
    int i = blockIdx.x * 256 + t;
    int v = (i < n) ? cnt[i] : 0;
    sh[t] = v;
    __syncthreads();
#pragma unroll
    for (int off = 1; off < 256; off <<= 1) {
        int u = 0;
        if (t >= off) u = sh[t - off];
        __syncthreads();
        sh[t] += u;
        __syncthreads();
    }
    if (i < n) rowptr[i] = sh[t] - v;
    if (t == 255) bsum[blockIdx.x] = sh[255];
}

__global__ __launch_bounds__(256)
void scanB_k(int* __restrict__ bsum, int nb) {
    __shared__ int sh[256];
    int t = threadIdx.x;
    int v = (t < nb) ? bsum[t] : 0;
    sh[t] = v;
    __syncthreads();
#pragma unroll
    for (int off = 1; off < 256; off <<= 1) {
        int u = 0;
        if (t >= off) u = sh[t - off];
        __syncthreads();
        sh[t] += u;
        __syncthreads();
    }
    if (t < nb) bsum[t] = sh[t] - v;
}

__global__ __launch_bounds__(256)
void scanC_k(const int* __restrict__ cnt, const int* __restrict__ bsum,
             int* __restrict__ rowptr, int* __restrict__ cursor,
             float* __restrict__ dis, int n, int EN) {
    int i = blockIdx.x * 256 + threadIdx.x;
    if (i < n) {
        int r = rowptr[i] + bsum[blockIdx.x];
        rowptr[i] = r;
        cursor[i] = r;
        dis[i] = rsqrtf((float)cnt[i]);
    }
    if (i == 0) rowptr[n] = EN;
}

__global__ void scatter_k(const int* __restrict__ esrc, const int* __restrict__ edst,
                          int* __restrict__ cursor, int* __restrict__ colidx, int E, int EN) {
    int i = blockIdx.x * 256 + threadIdx.x;
    if (i >= EN) return;
    int s, d;
    if (i < E) { s = esrc[i]; d = edst[i]; }
    else       { s = i - E; d = s; }
    int pos = atomicAdd(&cursor[d], 1);
    colidx[pos] = s;
}

// ---------------- dense GEMM helpers ----------------

#define FMA4R(A_, xv, w0, w1, w2, w3)                                  \
    A_.x += xv.x * w0.x + xv.y * w1.x + xv.z * w2.x + xv.w * w3.x;     \
    A_.y += xv.x * w0.y + xv.y * w1.y + xv.z * w2.y + xv.w * w3.y;     \
    A_.z += xv.x * w0.z + xv.y * w1.z + xv.z * w2.z + xv.w * w3.z;     \
    A_.w += xv.x * w0.w + xv.y * w1.w + xv.z * w2.w + xv.w * w3.w;

template <int K, int M>
__device__ __forceinline__ void gemm4(const float* __restrict__ Ws,
                                      const float* xa, const float* xb,
                                      const float* xc, const float* xd, int c,
                                      float4& A, float4& B, float4& C, float4& D) {
#pragma unroll 4
    for (int k = 0; k < K; k += 4) {
        float4 va = ld4(xa + k), vb = ld4(xb + k), vc = ld4(xc + k), vd = ld4(xd + k);
        const float* wp = Ws + k * M + c;
        float4 w0 = ld4(wp), w1 = ld4(wp + M), w2 = ld4(wp + 2 * M), w3 = ld4(wp + 3 * M);
        FMA4R(A, va, w0, w1, w2, w3)
        FMA4R(B, vb, w0, w1, w2, w3)
        FMA4R(C, vc, w0, w1, w2, w3)
        FMA4R(D, vd, w0, w1, w2, w3)
    }
}

__device__ __forceinline__ float4 f4bias(float4 v, float4 b) {
    return make_float4(v.x + b.x, v.y + b.y, v.z + b.z, v.w + b.w);
}
__device__ __forceinline__ float4 f4relu(float4 v) {
    return make_float4(fmaxf(v.x, 0.f), fmaxf(v.y, 0.f), fmaxf(v.z, 0.f), fmaxf(v.w, 0.f));
}
__device__ __forceinline__ float4 f4bn(float4 v, float4 g, float4 b) {
    return make_float4(v.x * g.x + b.x, v.y * g.y + b.y, v.z * g.z + b.z, v.w * g.w + b.w);
}

// input stage: 3 weight sets, same X (K=64, M=128)
__global__ __launch_bounds__(256)
void lin3_k(const float* __restrict__ X,
            const float* __restrict__ W0, const float* __restrict__ b0, float* __restrict__ Y0,
            const float* __restrict__ W1, const float* __restrict__ b1, float* __restrict__ Y1,
            const float* __restrict__ W2, const float* __restrict__ b2, float* __restrict__ Y2,
            int n, int gper) {
    constexpr int K = 64, M = 128, CG = 32, RPB = 8;
    int set = blockIdx.x / gper, blk = blockIdx.x % gper;
    const float* W = set == 0 ? W0 : (set == 1 ? W1 : W2);
    const float* bi = set == 0 ? b0 : (set == 1 ? b1 : b2);
    float* Y = set == 0 ? Y0 : (set == 1 ? Y1 : Y2);
    __shared__ float Ws[K * M];
    for (int i = threadIdx.x; i < K * M; i += 256) Ws[i] = W[i];
    __syncthreads();
    int cg = threadIdx.x % CG, r = threadIdx.x / CG, c = cg * 4;
    int ra = blk * (4 * RPB) + r, rb = ra + RPB, rc = ra + 2 * RPB, rd = ra + 3 * RPB;
    const float* xa = X + (size_t)(ra < n ? ra : 0) * K;
    const float* xb = X + (size_t)(rb < n ? rb : 0) * K;
    const float* xc = X + (size_t)(rc < n ? rc : 0) * K;
    const float* xd = X + (size_t)(rd < n ? rd : 0) * K;
    float4 A = f4z(), B = f4z(), C = f4z(), D = f4z();
    gemm4<K, M>(Ws, xa, xb, xc, xd, c, A, B, C, D);
    float4 bv = ld4(bi + c);
    A = f4bias(A, bv); B = f4bias(B, bv); C = f4bias(C, bv); D = f4bias(D, bv);
    if (ra < n) st4(Y + (size_t)ra * M + c, A);
    if (rb < n) st4(Y + (size_t)rb * M + c, B);
    if (rc < n) st4(Y + (size_t)rc * M + c, C);
    if (rd < n) st4(Y + (size_t)rd * M + c, D);
}

// per-layer pair: gcn half (Xg@Wg -> fp16 Yg), gat half (Xa@Wa -> fp16 Ya + attn dots)
// 8-row register blocking, K-split 32 KB LDS staging (2 passes).
__global__ __launch_bounds__(256, 4)
void dual128_k(const float* __restrict__ Xg, const float* __restrict__ Wg, __half* __restrict__ Yg,
               const float* __restrict__ Xa, const float* __restrict__ Wa, __half* __restrict__ Ya,
               const float* __restrict__ asrc, const float* __restrict__ adst,
               float* __restrict__ avp, float* __restrict__ bvp, int hh,
               int n, int gper) {
    constexpr int K = 128, M = 128, CG = 32, NR = 8;   // 64 rows/block
    bool gat = blockIdx.x >= gper;
    int blk = gat ? blockIdx.x - gper : blockIdx.x;
    const float* X = gat ? Xa : Xg;
    const float* W = gat ? Wa : Wg;
    __half* Y = gat ? Ya : Yg;
    __shared__ float Ws[64 * M];   // 32 KB half-K tile
    int cg = threadIdx.x % CG, r = threadIdx.x / CG, c = cg * 4;
    int row0 = blk * 64 + r * NR;
    const float* xr[NR];
#pragma unroll
    for (int j = 0; j < NR; ++j) {
        int rr = row0 + j;
        xr[j] = X + (size_t)(rr < n ? rr : 0) * K;
    }
    float4 acc[NR];
#pragma unroll
    for (int j = 0; j < NR; ++j) acc[j] = f4z();
    for (int kb = 0; kb < 2; ++kb) {
        if (kb) __syncthreads();
        for (int i = threadIdx.x; i < 64 * M; i += 256) Ws[i] = W[kb * 64 * M + i];
        __syncthreads();
        const int ko = kb * 64;
#pragma unroll 4
        for (int k = 0; k < 64; k += 4) {
            const float* wp = Ws + k * M + c;
            float4 w0 = ld4(wp), w1 = ld4(wp + M), w2 = ld4(wp + 2 * M), w3 = ld4(wp + 3 * M);
#pragma unroll
            for (int j = 0; j < NR; ++j) {
                float4 xv = ld4(xr[j] + ko + k);
                FMA4R(acc[j], xv, w0, w1, w2, w3)
            }
        }
    }
#pragma unroll
    for (int j = 0; j < NR; ++j) {
        int rr = row0 + j;
        if (rr < n) sth4(Y + (size_t)rr * M + c, acc[j]);
    }
    if (gat) {
        float4 as = ld4(asrc + c), ad = ld4(adst + c);
        float sa[NR], sd[NR];
#pragma unroll
        for (int j = 0; j < NR; ++j) {
            sa[j] = acc[j].x * as.x + acc[j].y * as.y + acc[j].z * as.z + acc[j].w * as.w;
            sd[j] = acc[j].x * ad.x + acc[j].y * ad.y + acc[j].z * ad.z + acc[j].w * ad.w;
        }
        int gw = 32 / hh;   // lanes per head (8 or 32)
        for (int off = 1; off < gw; off <<= 1) {
#pragma unroll
            for (int j = 0; j < NR; ++j) {
                sa[j] += __shfl_xor(sa[j], off);
                sd[j] += __shfl_xor(sd[j], off);
            }
        }
        if ((cg & (gw - 1)) == 0) {
            int h = cg / gw;
#pragma unroll
            for (int j = 0; j < NR; ++j) {
                int rr = row0 + j;
                if (rr < n) { avp[rr * hh + h] = sa[j]; bvp[rr * hh + h] = sd[j]; }
            }
        }
    }
}

// MLP-tail pair: two independent (X,W,b[,bn]) sets
template <int K, int M>
__global__ __launch_bounds__(256)
void tail2_k(const float* __restrict__ X0, const float* __restrict__ W0, const float* __restrict__ b0,
             const float* __restrict__ g0, const float* __restrict__ bb0, float* __restrict__ Y0,
             const float* __restrict__ X1, const float* __restrict__ W1, const float* __restrict__ b1,
             const float* __restrict__ g1, const float* __restrict__ bb1, float* __restrict__ Y1,
             int n, int gper, int do_relu) {
    constexpr int CG = M / 4, RPB = 256 / CG;
    bool s1 = blockIdx.x >= gper;
    int blk = s1 ? blockIdx.x - gper : blockIdx.x;
    const float* X = s1 ? X1 : X0;
    const float* W = s1 ? W1 : W0;
    const float* bi = s1 ? b1 : b0;
    const float* bg = s1 ? g1 : g0;
    const float* bb = s1 ? bb1 : bb0;
    float* Y = s1 ? Y1 : Y0;
    __shared__ float Ws[K * M];
    for (int i = threadIdx.x; i < K * M; i += 256) Ws[i] = W[i];
    __syncthreads();
    int cg = threadIdx.x % CG, r = threadIdx.x / CG, c = cg * 4;
    int ra = blk * (4 * RPB) + r, rb = ra + RPB, rc = ra + 2 * RPB, rd = ra + 3 * RPB;
    const float* xa = X + (size_t)(ra < n ? ra : 0) * K;
    const float* xb = X + (size_t)(rb < n ? rb : 0) * K;
    const float* xc = X + (size_t)(rc < n ? rc : 0) * K;
    const float* xd = X + (size_t)(rd < n ? rd : 0) * K;
    float4 A = f4z(), B = f4z(), C = f4z(), D = f4z();
    gemm4<K, M>(Ws, xa, xb, xc, xd, c, A, B, C, D);
    float4 bv = ld4(bi + c);
    A = f4bias(A, bv); B = f4bias(B, bv); C = f4bias(C, bv); D = f4bias(D, bv);
    if (do_relu) { A = f4relu(A); B = f4relu(B); C = f4relu(C); D = f4relu(D); }
    if (bg) {
        float4 g = ld4(bg + c);
        g = make_float4(g.x * RSQ_BN, g.y * RSQ_BN, g.z * RSQ_BN, g.w * RSQ_BN);
        float4 bbv = ld4(bb + c);
        A = f4bn(A, g, bbv); B = f4bn(B, g, bbv); C = f4bn(C, g, bbv); D = f4bn(D, g, bbv);
    }
    if (ra < n) st4(Y + (size_t)ra * M + c, A);
    if (rb < n) st4(Y + (size_t)rb * M + c, B);
    if (rc < n) st4(Y + (size_t)rc * M + c, C);
    if (rd < n) st4(Y + (size_t)rd * M + c, D);
}

// final: blend(0.6*XA+0.4*XB) @ fin -> relu -> bn -> @fin2 -> out[n,2]
__global__ __launch_bounds__(256)
void linF_k(const float* __restrict__ XA, const float* __restrict__ XB,
            const float* __restrict__ W, const float* __restrict__ bi,
            const float* __restrict__ bg, const float* __restrict__ bb,
            const float* __restrict__ w2, const float* __restrict__ b2,
            float* __restrict__ out, int n) {
    constexpr int K = 128, M = 64, CG = 16, RPB = 16;
    __shared__ float Ws[K * M];
    for (int i = threadIdx.x; i < K * M; i += 256) Ws[i] = W[i];
    __syncthreads();
    int cg = threadIdx.x % CG, r = threadIdx.x / CG, c = cg * 4;
    int ra = blockIdx.x * (4 * RPB) + r, rb = ra + RPB, rc = ra + 2 * RPB, rd = ra + 3 * RPB;
    const float* xa = XA + (size_t)(ra < n ? ra : 0) * K;
    const float* xb = XA + (size_t)(rb < n ? rb : 0) * K;
    const float* xc = XA + (size_t)(rc < n ? rc : 0) * K;
    const float* xd = XA + (size_t)(rd < n ? rd : 0) * K;
    const float* ya = XB + (size_t)(ra < n ? ra : 0) * K;
    const float* yb = XB + (size_t)(rb < n ? rb : 0) * K;
    const float* yc = XB + (size_t)(rc < n ? rc : 0) * K;
    const float* yd = XB + (size_t)(rd < n ? rd : 0) * K;
    float4 A = f4z(), B = f4z(), C = f4z(), D = f4z();
#pragma unroll 4
    for (int k = 0; k < K; k += 4) {
        float4 va = ld4(xa + k), vb = ld4(xb + k), vc = ld4(xc + k), vd = ld4(xd + k);
        float4 ua = ld4(ya + k), ub = ld4(yb + k), uc = ld4(yc + k), ud = ld4(yd + k);
        va = make_float4(0.6f * va.x + 0.4f * ua.x, 0.6f * va.y + 0.4f * ua.y,
                         0.6f * va.z + 0.4f * ua.z, 0.6f * va.w + 0.4f * ua.w);
        vb = make_float4(0.6f * vb.x + 0.4f * ub.x, 0.6f * vb.y + 0.4f * ub.y,
                         0.6f * vb.z + 0.4f * ub.z, 0.6f * vb.w + 0.4f * ub.w);
        vc = make_float4(0.6f * vc.x + 0.4f * uc.x, 0.6f * vc.y + 0.4f * uc.y,
                         0.6f * vc.z + 0.4f * uc.z, 0.6f * vc.w + 0.4f * uc.w);
        vd = make_float4(0.6f * vd.x + 0.4f * ud.x, 0.6f * vd.y + 0.4f * ud.y,
                         0.6f * vd.z + 0.4f * ud.z, 0.6f * vd.w + 0.4f * ud.w);
        const float* wp = Ws + k * M + c;
        float4 w0 = ld4(wp), w1 = ld4(wp + M), w2v = ld4(wp + 2 * M), w3 = ld4(wp + 3 * M);
        FMA4R(A, va, w0, w1, w2v, w3)
        FMA4R(B, vb, w0, w1, w2v, w3)
        FMA4R(C, vc, w0, w1, w2v, w3)
        FMA4R(D, vd, w0, w1, w2v, w3)
    }
    float4 bv = ld4(bi + c);
    A = f4relu(f4bias(A, bv)); B = f4relu(f4bias(B, bv));
    C = f4relu(f4bias(C, bv)); D = f4relu(f4bias(D, bv));
    float4 g = ld4(bg + c);
    g = make_float4(g.x * RSQ_BN, g.y * RSQ_BN, g.z * RSQ_BN, g.w * RSQ_BN);
    float4 bbv = ld4(bb + c);
    A = f4bn(A, g, bbv); B = f4bn(B, g, bbv); C = f4bn(C, g, bbv); D = f4bn(D, g, bbv);
    float w20 = w2[2 * c], w21 = w2[2 * c + 1];
    float w22 = w2[2 * c + 2], w23 = w2[2 * c + 3];
    float w24 = w2[2 * c + 4], w25 = w2[2 * c + 5];
    float w26 = w2[2 * c + 6], w27 = w2[2 * c + 7];
    float p0[4], p1[4];
    p0[0] = A.x * w20 + A.y * w22 + A.z * w24 + A.w * w26;
    p1[0] = A.x * w21 + A.y * w23 + A.z * w25 + A.w * w27;
    p0[1] = B.x * w20 + B.y * w22 + B.z * w24 + B.w * w26;
    p1[1] = B.x * w21 + B.y * w23 + B.z * w25 + B.w * w27;
    p0[2] = C.x * w20 + C.y * w22 + C.z * w24 + C.w * w26;
    p1[2] = C.x * w21 + C.y * w23 + C.z * w25 + C.w * w27;
    p0[3] = D.x * w20 + D.y * w22 + D.z * w24 + D.w * w26;
    p1[3] = D.x * w21 + D.y * w23 + D.z * w25 + D.w * w27;
    for (int off = 1; off < CG; off <<= 1) {
#pragma unroll
        for (int j = 0; j < 4; ++j) {
            p0[j] += __shfl_xor(p0[j], off);
            p1[j] += __shfl_xor(p1[j], off);
        }
    }
    if (cg == 0) {
        int rows[4] = {ra, rb, rc, rd};
#pragma unroll
        for (int j = 0; j < 4; ++j) {
            if (rows[j] < n) {
                out[rows[j] * 2] = p0[j] + b2[0];
                out[rows[j] * 2 + 1] = p1[j] + b2[1];
            }
        }
    }
}

// ---------------- merged sparse aggregation: gcn half + gat half ----------------
// 16 lanes/node, 8 cols (16B fp16) per lane; 8x unrolled edge loop.

__global__ __launch_bounds__(256)
void dual_gather_k(const int* __restrict__ rowptr, const int* __restrict__ colidx,
                   const float* __restrict__ dis,
                   const __half* __restrict__ Tg, const float* __restrict__ gbias,
                   const float* __restrict__ gbng, const float* __restrict__ gbnb,
                   const float* __restrict__ res, float* __restrict__ Yg,
                   const __half* __restrict__ Ta, const float* __restrict__ avp,
                   const float* __restrict__ bvp, const float* __restrict__ abias,
                   const float* __restrict__ abng, const float* __restrict__ abnb,
                   const float* __restrict__ fimp, float* __restrict__ Ya,
                   int n, int gper, int hh, int log2C) {
    bool gat = blockIdx.x >= gper;
    int blk = gat ? blockIdx.x - gper : blockIdx.x;
    int idx = blk * 256 + threadIdx.x;
    int i = idx >> 4;
    if (i >= n) return;
    int c = (idx & 15) * 8;
    int p0 = rowptr[i], p1 = rowptr[i + 1];
    float4 lo = f4z(), hi = f4z();

#define ACC8(qq, ww)                                                            \
    {                                                                           \
        float4 t0 = h4f(make_uint2(qq.x, qq.y)), t1 = h4f(make_uint2(qq.z, qq.w)); \
        lo.x += t0.x * ww; lo.y += t0.y * ww; lo.z += t0.z * ww; lo.w += t0.w * ww; \
        hi.x += t1.x * ww; hi.y += t1.y * ww; hi.z += t1.z * ww; hi.w += t1.w * ww; \
    }

    if (!gat) {
        int p = p0;
        for (; p + 8 <= p1; p += 8) {
            int s[8]; float w[8]; uint4 q[8];
#pragma unroll
            for (int j = 0; j < 8; ++j) s[j] = colidx[p + j];
#pragma unroll
            for (int j = 0; j < 8; ++j) w[j] = dis[s[j]];
#pragma unroll
            for (int j = 0; j < 8; ++j)
                q[j] = *reinterpret_cast<const uint4*>(Tg + (size_t)s[j] * 128 + c);
#pragma unroll
            for (int j = 0; j < 8; ++j) ACC8(q[j], w[j])
        }
        for (; p < p1; ++p) {
            int s0 = colidx[p];
            float w0 = dis[s0];
            uint4 q0 = *reinterpret_cast<const uint4*>(Tg + (size_t)s0 * 128 + c);
            ACC8(q0, w0)
        }
        float di = dis[i];
        float4 b0 = ld4(gbias + c), b1 = ld4(gbias + c + 4);
        lo = make_float4(lo.x * di + b0.x, lo.y * di + b0.y, lo.z * di + b0.z, lo.w * di + b0.w);
        hi = make_float4(hi.x * di + b1.x, hi.y * di + b1.y, hi.z * di + b1.z, hi.w * di + b1.w);
        float4 g0 = ld4(gbng + c), g1 = ld4(gbng + c + 4);
        g0 = make_float4(g0.x * RSQ_BN, g0.y * RSQ_BN, g0.z * RSQ_BN, g0.w * RSQ_BN);
        g1 = make_float4(g1.x * RSQ_BN, g1.y * RSQ_BN, g1.z * RSQ_BN, g1.w * RSQ_BN);
        float4 h0 = ld4(gbnb + c), h1 = ld4(gbnb + c + 4);
        lo = f4relu(f4bn(lo, g0, h0));
        hi = f4relu(f4bn(hi, g1, h1));
        if (res) {
            float4 r0 = ld4(res + (size_t)i * 128 + c), r1 = ld4(res + (size_t)i * 128 + c + 4);
            lo = f4bias(lo, r0); hi = f4bias(hi, r1);
        }
        st4(Yg + (size_t)i * 128 + c, lo);
        st4(Yg + (size_t)i * 128 + c + 4, hi);
    } else {
        int h = c >> log2C;
        float ad = bvp[i * hh + h];
        float m = -3.0e38f, s = 0.f;
        int p = p0;
        for (; p + 8 <= p1; p += 8) {
            int sx[8]; float e[8]; uint4 q[8];
#pragma unroll
            for (int j = 0; j < 8; ++j) sx[j] = colidx[p + j];
#pragma unroll
            for (int j = 0; j < 8; ++j) e[j] = leaky02(avp[sx[j] * hh + h] + ad);
#pragma unroll
            for (int j = 0; j < 8; ++j)
                q[j] = *reinterpret_cast<const uint4*>(Ta + (size_t)sx[j] * 128 + c);
            float mc = fmaxf(fmaxf(fmaxf(e[0], e[1]), fmaxf(e[2], e[3])),
                             fmaxf(fmaxf(e[4], e[5]), fmaxf(e[6], e[7])));
            float mn = fmaxf(m, mc);
            float scale = expf(m - mn);
            float wsum = 0.f;
            lo = make_float4(lo.x * scale, lo.y * scale, lo.z * scale, lo.w * scale);
            hi = make_float4(hi.x * scale, hi.y * scale, hi.z * scale, hi.w * scale);
#pragma unroll
            for (int j = 0; j < 8; ++j) {
                float wj = expf(e[j] - mn);
                wsum += wj;
                ACC8(q[j], wj)
            }
            s = s * scale + wsum;
            m = mn;
        }
        for (; p < p1; ++p) {
            int s0 = colidx[p];
            float e0 = leaky02(avp[s0 * hh + h] + ad);
            float mn = fmaxf(m, e0);
            float scale = expf(m - mn);
            float w0 = expf(e0 - mn);
            s = s * scale + w0;
            lo = make_float4(lo.x * scale, lo.y * scale, lo.z * scale, lo.w * scale);
            hi = make_float4(hi.x * scale, hi.y * scale, hi.z * scale, hi.w * scale);
            uint4 q0 = *reinterpret_cast<const uint4*>(Ta + (size_t)s0 * 128 + c);
            ACC8(q0, w0)
            m = mn;
        }
        float si = 1.f / (s + 1e-16f);
        float4 b0 = ld4(abias + c), b1 = ld4(abias + c + 4);
        lo = make_float4(lo.x * si + b0.x, lo.y * si + b0.y, lo.z * si + b0.z, lo.w * si + b0.w);
        hi = make_float4(hi.x * si + b1.x, hi.y * si + b1.y, hi.z * si + b1.z, hi.w * si + b1.w);
        float4 g0 = ld4(abng + c), g1 = ld4(abng + c + 4);
        g0 = make_float4(g0.x * RSQ_BN, g0.y * RSQ_BN, g0.z * RSQ_BN, g0.w * RSQ_BN);
        g1 = make_float4(g1.x * RSQ_BN, g1.y * RSQ_BN, g1.z * RSQ_BN, g1.w * RSQ_BN);
        float4 h0 = ld4(abnb + c), h1 = ld4(abnb + c + 4);
        lo = f4bn(lo, g0, h0);
        hi = f4bn(hi, g1, h1);
        lo.x = lo.x > 0.f ? lo.x : expm1f(lo.x);
        lo.y = lo.y > 0.f ? lo.y : expm1f(lo.y);
        lo.z = lo.z > 0.f ? lo.z : expm1f(lo.z);
        lo.w = lo.w > 0.f ? lo.w : expm1f(lo.w);
        hi.x = hi.x > 0.f ? hi.x : expm1f(hi.x);
        hi.y = hi.y > 0.f ? hi.y : expm1f(hi.y);
        hi.z = hi.z > 0.f ? hi.z : expm1f(hi.z);
        hi.w = hi.w > 0.f ? hi.w : expm1f(hi.w);
        if (fimp) {
            float4 f0 = ld4(fimp + c), f1 = ld4(fimp + c + 4);
            lo = make_float4(lo.x * f0.x, lo.y * f0.y, lo.z * f0.z, lo.w * f0.w);
            hi = make_float4(hi.x * f1.x, hi.y * f1.y, hi.z * f1.z, hi.w * f1.w);
        }
        st4(Ya + (size_t)i * 128 + c, lo);
        st4(Ya + (size_t)i * 128 + c + 4, hi);
    }
#undef ACC8
}

// ---------------- host orchestration ----------------

static inline int cdiv(int a, int b) { return (a + b - 1) / b; }

extern "C" void kernel_launch(void* const* d_in, const int* in_sizes, int n_in,
                              void* d_out, int out_size, void* d_ws, size_t ws_size,
                              hipStream_t stream) {
    const float* x       = (const float*)d_in[0];
    const int*   ei      = (const int*)d_in[1];
    const float* gcn_in_w = (const float*)d_in[2];
    const float* gcn_in_b = (const float*)d_in[3];
    const float* gcn_res_w = (const float*)d_in[4];
    const float* gcn_res_b = (const float*)d_in[5];
    const float* gcn_w   = (const float*)d_in[6];
    const float* gcn_b   = (const float*)d_in[7];
    const float* gcn_bn_g = (const float*)d_in[8];
    const float* gcn_bn_b = (const float*)d_in[9];
    const float* gcn_c1w = (const float*)d_in[10];
    const float* gcn_c1b = (const float*)d_in[11];
    const float* gcn_c2w = (const float*)d_in[12];
    const float* gcn_c2b = (const float*)d_in[13];
    const float* gcn_c3w = (const float*)d_in[14];
    const float* gcn_c3b = (const float*)d_in[15];
    const float* gat_in_w = (const float*)d_in[16];
    const float* gat_in_b = (const float*)d_in[17];
    const float* gat_w   = (const float*)d_in[18];
    const float* gat_asrc = (const float*)d_in[19];
    const float* gat_adst = (const float*)d_in[20];
    const float* gat_b   = (const float*)d_in[21];
    const float* gat_bn_g = (const float*)d_in[22];
    const float* gat_bn_b = (const float*)d_in[23];
    const float* feat_imp = (const float*)d_in[24];
    const float* gat_c1w = (const float*)d_in[25];
    const float* gat_c1b = (const float*)d_in[26];
    const float* gat_cbn_g = (const float*)d_in[27];
    const float* gat_cbn_b = (const float*)d_in[28];
    const float* gat_c2w = (const float*)d_in[29];
    const float* gat_c2b = (const float*)d_in[30];
    const float* gat_c3w = (const float*)d_in[31];
    const float* gat_c3b = (const float*)d_in[32];
    const float* fin_w   = (const float*)d_in[33];
    const float* fin_b   = (const float*)d_in[34];
    const float* fin_bn_g = (const float*)d_in[35];
    const float* fin_bn_b = (const float*)d_in[36];
    const float* fin2_w  = (const float*)d_in[37];
    const float* fin2_b  = (const float*)d_in[38];

    const int N = in_sizes[0] / 64;
    const int E = in_sizes[1] / 2;
    const int EN = E + N;
    const int* esrc = ei;
    const int* edst = ei + E;

    // workspace carve (256B aligned)
    char* wp = (char*)d_ws;
    auto alloc = [&](size_t bytes) -> void* {
        void* p = (void*)wp;
        wp += (bytes + 255) & ~(size_t)255;
        return p;
    };
    int* cnt    = (int*)alloc((size_t)N * 4);
    int* rowptr = (int*)alloc((size_t)(N + 1) * 4);
    int* cursor = (int*)alloc((size_t)N * 4);
    int* bsum   = (int*)alloc((size_t)256 * 4);
    int* colidx = (int*)alloc((size_t)EN * 4);
    float* dis  = (float*)alloc((size_t)N * 4);
    float* A    = (float*)alloc((size_t)N * 128 * 4);   // gcn ping / GOUT reuse
    float* B    = (float*)alloc((size_t)N * 128 * 4);   // gcn pong
    float* G    = (float*)alloc((size_t)N * 128 * 4);   // gat ping / AOUT reuse
    float* H    = (float*)alloc((size_t)N * 128 * 4);   // gat pong
    float* R    = (float*)alloc((size_t)N * 128 * 4);   // gcn residual
    __half* Th1 = (__half*)alloc((size_t)N * 128 * 2);  // aliased as h1g after layers
    __half* Th2 = (__half*)alloc((size_t)N * 128 * 2);  // aliased as h1a after layers
    float* h2g  = (float*)alloc((size_t)N * 32 * 4);
    float* h2a  = (float*)alloc((size_t)N * 32 * 4);
    float* avv  = (float*)alloc((size_t)N * 4 * 4);
    float* bvv  = (float*)alloc((size_t)N * 4 * 4);
    float* h1g = (float*)Th1;   // N*64*4 == N*128*2 bytes
    float* h1a = (float*)Th2;

    // ---- CSR build ----
    const int nScanB = cdiv(N, 256);
    zero_i32_k<<<cdiv(N, 256), 256, 0, stream>>>(cnt, N);
    hist_k<<<cdiv(EN, 256), 256, 0, stream>>>(edst, cnt, E, EN);
    scanA_k<<<nScanB, 256, 0, stream>>>(cnt, rowptr, bsum, N);
    scanB_k<<<1, 256, 0, stream>>>(bsum, nScanB);
    scanC_k<<<nScanB, 256, 0, stream>>>(cnt, bsum, rowptr, cursor, dis, N, EN);
    scatter_k<<<cdiv(EN, 256), 256, 0, stream>>>(esrc, edst, cursor, colidx, E, EN);

    const int g32r  = cdiv(N, 32);    // M=128, 4-row blocks (lin3 / tail 32->128)
    const int g64r  = cdiv(N, 64);    // M=64 tails / dual128 (64 rows/block)
    const int g128r = cdiv(N, 128);   // M=32
    const int gG    = cdiv(N, 16);    // gather: 16 nodes/block

    // ---- input stage: gcn_in -> A, gcn_res -> R, gat_in -> G ----
    lin3_k<<<3 * g32r, 256, 0, stream>>>(x, gcn_in_w, gcn_in_b, A,
                                         gcn_res_w, gcn_res_b, R,
                                         gat_in_w, gat_in_b, G, N, g32r);

    // ---- 3 layers, both branches in lockstep ----
    const int heads_arr[3] = {4, 4, 1};
    float* gcur = A; float* gnxt = B;
    float* acur = G; float* anxt = H;
    for (int i = 0; i < 3; ++i) {
        int hh = heads_arr[i];
        int log2C = (hh == 4) ? 5 : 7;
        dual128_k<<<2 * g64r, 256, 0, stream>>>(gcur, gcn_w + (size_t)i * 16384, Th1,
                                                acur, gat_w + (size_t)i * 16384, Th2,
                                                gat_asrc + i * 128, gat_adst + i * 128,
                                                avv, bvv, hh, N, g64r);
        dual_gather_k<<<2 * gG, 256, 0, stream>>>(rowptr, colidx, dis,
                                                  Th1, gcn_b + i * 128, gcn_bn_g + i * 128,
                                                  gcn_bn_b + i * 128, (i == 1) ? R : nullptr, gnxt,
                                                  Th2, avv, bvv, gat_b + i * 128,
                                                  gat_bn_g + i * 128, gat_bn_b + i * 128,
                                                  (i == 2) ? feat_imp : nullptr, anxt,
                                                  N, gG, hh, log2C);
        float* t = gcur; gcur = gnxt; gnxt = t;
        t = acur; acur = anxt; anxt = t;
    }
    // gcur = gcn final xp (B), acur = gat final xg (H)

    // ---- MLP tails (pairs) ----  (h1g/h1a alias Th1/Th2 — Th no longer needed)
    tail2_k<128, 64><<<2 * g64r, 256, 0, stream>>>(
        gcur, gcn_c1w, gcn_c1b, nullptr, nullptr, h1g,
        acur, gat_c1w, gat_c1b, gat_cbn_g, gat_cbn_b, h1a, N, g64r, 1);
    tail2_k<64, 32><<<2 * g128r, 256, 0, stream>>>(
        h1g, gcn_c2w, gcn_c2b, nullptr, nullptr, h2g,
        h1a, gat_c2w, gat_c2b, nullptr, nullptr, h2a, N, g128r, 1);
    tail2_k<32, 128><<<2 * g32r, 256, 0, stream>>>(
        h2g, gcn_c3w, gcn_c3b, nullptr, nullptr, A,
        h2a, gat_c3w, gat_c3b, nullptr, nullptr, G, N, g32r, 0);

    // ---- fusion tail: blend + fin linear + bn + classifier ----
    linF_k<<<g64r, 256, 0, stream>>>(A, G, fin_w, fin_b, fin_bn_g, fin_bn_b,
                                     fin2_w, fin2_b, (float*)d_out, N);
}

// Round 7
// 591.042 us; speedup vs baseline: 1.6815x; 1.6815x over previous
//
#include <hip/hip_runtime.h>
#include <hip/hip_fp16.h>

// BN scale constant: 1/sqrt(1+1e-5)
#define RSQ_BN 0.9999950000374997f

__device__ __forceinline__ float leaky02(float x) { return x > 0.f ? x : 0.2f * x; }

__device__ __forceinline__ float4 ld4(const float* p) {
    return *reinterpret_cast<const float4*>(p);
}
__device__ __forceinline__ void st4(float* p, float4 v) {
    *reinterpret_cast<float4*>(p) = v;
}
__device__ __forceinline__ void sth4(__half* p, float4 v) {
    union { uint2 u; __half2 h[2]; } pk;
    pk.h[0] = __floats2half2_rn(v.x, v.y);
    pk.h[1] = __floats2half2_rn(v.z, v.w);
    *reinterpret_cast<uint2*>(p) = pk.u;
}
__device__ __forceinline__ float4 h4f(uint2 u) {
    union { uint2 u; __half2 h[2]; } pk;
    pk.u = u;
    float2 lo = __half22float2(pk.h[0]);
    float2 hi = __half22float2(pk.h[1]);
    return make_float4(lo.x, lo.y, hi.x, hi.y);
}
__device__ __forceinline__ float4 f4z() { return make_float4(0.f, 0.f, 0.f, 0.f); }

// ---------------- CSR build ----------------

__global__ void zero_i32_k(int* __restrict__ p, int n) {
    int i = blockIdx.x * 256 + threadIdx.x;
    if (i < n) p[i] = 0;
}

__global__ void hist_k(const int* __restrict__ edst, int* __restrict__ cnt, int E, int EN) {
    int i = blockIdx.x * 256 + threadIdx.x;
    if (i >= EN) return;
    int d = (i < E) ? edst[i] : (i - E);   // self-loop for i>=E
    atomicAdd(&cnt[d], 1);
}

__global__ __launch_bounds__(256)
void scanA_k(const int* __restrict__ cnt, int* __restrict__ rowptr,
             int* __restrict__ bsum, int n) {
    __shared__ int sh[256];
    int t = threadIdx.x;
    int i = blockIdx.x * 256 + t;
    int v = (i < n) ? cnt[i] : 0;
    sh[t] = v;
    __syncthreads();
#pragma unroll
    for (int off = 1; off < 256; off <<= 1) {
        int u = 0;
        if (t >= off) u = sh[t - off];
        __syncthreads();
        sh[t] += u;
        __syncthreads();
    }
    if (i < n) rowptr[i] = sh[t] - v;
    if (t == 255) bsum[blockIdx.x] = sh[255];
}

__global__ __launch_bounds__(256)
void scanB_k(int* __restrict__ bsum, int nb) {
    __shared__ int sh[256];
    int t = threadIdx.x;
    int v = (t < nb) ? bsum[t] : 0;
    sh[t] = v;
    __syncthreads();
#pragma unroll
    for (int off = 1; off < 256; off <<= 1) {
        int u = 0;
        if (t >= off) u = sh[t - off];
        __syncthreads();
        sh[t] += u;
        __syncthreads();
    }
    if (t < nb) bsum[t] = sh[t] - v;
}

__global__ __launch_bounds__(256)
void scanC_k(const int* __restrict__ cnt, const int* __restrict__ bsum,
             int* __restrict__ rowptr, int* __restrict__ cursor,
             float* __restrict__ dis, int n, int EN) {
    int i = blockIdx.x * 256 + threadIdx.x;
    if (i < n) {
        int r = rowptr[i] + bsum[blockIdx.x];
        rowptr[i] = r;
        cursor[i] = r;
        dis[i] = rsqrtf((float)cnt[i]);
    }
    if (i == 0) rowptr[n] = EN;
}

__global__ void scatter_k(const int* __restrict__ esrc, const int* __restrict__ edst,
                          int* __restrict__ cursor, int* __restrict__ colidx, int E, int EN) {
    int i = blockIdx.x * 256 + threadIdx.x;
    if (i >= EN) return;
    int s, d;
    if (i < E) { s = esrc[i]; d = edst[i]; }
    else       { s = i - E; d = s; }
    int pos = atomicAdd(&cursor[d], 1);
    colidx[pos] = s;
}

// ---------------- dense GEMM helpers ----------------

#define FMA4R(A_, xv, w0, w1, w2, w3)                                  \
    A_.x += xv.x * w0.x + xv.y * w1.x + xv.z * w2.x + xv.w * w3.x;     \
    A_.y += xv.x * w0.y + xv.y * w1.y + xv.z * w2.y + xv.w * w3.y;     \
    A_.z += xv.x * w0.z + xv.y * w1.z + xv.z * w2.z + xv.w * w3.z;     \
    A_.w += xv.x * w0.w + xv.y * w1.w + xv.z * w2.w + xv.w * w3.w;

template <int K, int M>
__device__ __forceinline__ void gemm4(const float* __restrict__ Ws,
                                      const float* xa, const float* xb,
                                      const float* xc, const float* xd, int c,
                                      float4& A, float4& B, float4& C, float4& D) {
#pragma unroll 4
    for (int k = 0; k < K; k += 4) {
        float4 va = ld4(xa + k), vb = ld4(xb + k), vc = ld4(xc + k), vd = ld4(xd + k);
        const float* wp = Ws + k * M + c;
        float4 w0 = ld4(wp), w1 = ld4(wp + M), w2 = ld4(wp + 2 * M), w3 = ld4(wp + 3 * M);
        FMA4R(A, va, w0, w1, w2, w3)
        FMA4R(B, vb, w0, w1, w2, w3)
        FMA4R(C, vc, w0, w1, w2, w3)
        FMA4R(D, vd, w0, w1, w2, w3)
    }
}

__device__ __forceinline__ float4 f4bias(float4 v, float4 b) {
    return make_float4(v.x + b.x, v.y + b.y, v.z + b.z, v.w + b.w);
}
__device__ __forceinline__ float4 f4relu(float4 v) {
    return make_float4(fmaxf(v.x, 0.f), fmaxf(v.y, 0.f), fmaxf(v.z, 0.f), fmaxf(v.w, 0.f));
}
__device__ __forceinline__ float4 f4bn(float4 v, float4 g, float4 b) {
    return make_float4(v.x * g.x + b.x, v.y * g.y + b.y, v.z * g.z + b.z, v.w * g.w + b.w);
}

// input stage: 3 weight sets, same X (K=64, M=128)
__global__ __launch_bounds__(256)
void lin3_k(const float* __restrict__ X,
            const float* __restrict__ W0, const float* __restrict__ b0, float* __restrict__ Y0,
            const float* __restrict__ W1, const float* __restrict__ b1, float* __restrict__ Y1,
            const float* __restrict__ W2, const float* __restrict__ b2, float* __restrict__ Y2,
            int n, int gper) {
    constexpr int K = 64, M = 128, CG = 32, RPB = 8;
    int set = blockIdx.x / gper, blk = blockIdx.x % gper;
    const float* W = set == 0 ? W0 : (set == 1 ? W1 : W2);
    const float* bi = set == 0 ? b0 : (set == 1 ? b1 : b2);
    float* Y = set == 0 ? Y0 : (set == 1 ? Y1 : Y2);
    __shared__ float Ws[K * M];
    for (int i = threadIdx.x; i < K * M; i += 256) Ws[i] = W[i];
    __syncthreads();
    int cg = threadIdx.x % CG, r = threadIdx.x / CG, c = cg * 4;
    int ra = blk * (4 * RPB) + r, rb = ra + RPB, rc = ra + 2 * RPB, rd = ra + 3 * RPB;
    const float* xa = X + (size_t)(ra < n ? ra : 0) * K;
    const float* xb = X + (size_t)(rb < n ? rb : 0) * K;
    const float* xc = X + (size_t)(rc < n ? rc : 0) * K;
    const float* xd = X + (size_t)(rd < n ? rd : 0) * K;
    float4 A = f4z(), B = f4z(), C = f4z(), D = f4z();
    gemm4<K, M>(Ws, xa, xb, xc, xd, c, A, B, C, D);
    float4 bv = ld4(bi + c);
    A = f4bias(A, bv); B = f4bias(B, bv); C = f4bias(C, bv); D = f4bias(D, bv);
    if (ra < n) st4(Y + (size_t)ra * M + c, A);
    if (rb < n) st4(Y + (size_t)rb * M + c, B);
    if (rc < n) st4(Y + (size_t)rc * M + c, C);
    if (rd < n) st4(Y + (size_t)rd * M + c, D);
}

// per-layer pair: gcn half (Xg@Wg -> fp16 Yg), gat half (Xa@Wa -> fp16 Ya + attn dots)
// Round-5 register shape (4-row, ~124 VGPR, no spills) + K-split 32 KB LDS (2 passes)
// for doubled block residency. NO launch_bounds minimum — let the allocator breathe.
__global__ __launch_bounds__(256)
void dual128_k(const float* __restrict__ Xg, const float* __restrict__ Wg, __half* __restrict__ Yg,
               const float* __restrict__ Xa, const float* __restrict__ Wa, __half* __restrict__ Ya,
               const float* __restrict__ asrc, const float* __restrict__ adst,
               float* __restrict__ avp, float* __restrict__ bvp, int hh,
               int n, int gper) {
    constexpr int K = 128, M = 128, CG = 32, RPB = 8;   // 32 rows/block
    bool gat = blockIdx.x >= gper;
    int blk = gat ? blockIdx.x - gper : blockIdx.x;
    const float* X = gat ? Xa : Xg;
    const float* W = gat ? Wa : Wg;
    __half* Y = gat ? Ya : Yg;
    __shared__ float Ws[64 * M];   // 32 KB half-K tile
    int cg = threadIdx.x % CG, r = threadIdx.x / CG, c = cg * 4;
    int ra = blk * (4 * RPB) + r, rb = ra + RPB, rc = ra + 2 * RPB, rd = ra + 3 * RPB;
    const float* xa = X + (size_t)(ra < n ? ra : 0) * K;
    const float* xb = X + (size_t)(rb < n ? rb : 0) * K;
    const float* xc = X + (size_t)(rc < n ? rc : 0) * K;
    const float* xd = X + (size_t)(rd < n ? rd : 0) * K;
    float4 A = f4z(), B = f4z(), C = f4z(), D = f4z();
    for (int kb = 0; kb < 2; ++kb) {
        if (kb) __syncthreads();
        for (int i = threadIdx.x; i < 64 * M; i += 256) Ws[i] = W[kb * 64 * M + i];
        __syncthreads();
        const int ko = kb * 64;
#pragma unroll 4
        for (int k = 0; k < 64; k += 4) {
            float4 va = ld4(xa + ko + k), vb = ld4(xb + ko + k);
            float4 vc = ld4(xc + ko + k), vd = ld4(xd + ko + k);
            const float* wp = Ws + k * M + c;
            float4 w0 = ld4(wp), w1 = ld4(wp + M), w2 = ld4(wp + 2 * M), w3 = ld4(wp + 3 * M);
            FMA4R(A, va, w0, w1, w2, w3)
            FMA4R(B, vb, w0, w1, w2, w3)
            FMA4R(C, vc, w0, w1, w2, w3)
            FMA4R(D, vd, w0, w1, w2, w3)
        }
    }
    if (ra < n) sth4(Y + (size_t)ra * M + c, A);
    if (rb < n) sth4(Y + (size_t)rb * M + c, B);
    if (rc < n) sth4(Y + (size_t)rc * M + c, C);
    if (rd < n) sth4(Y + (size_t)rd * M + c, D);
    if (gat) {
        float4 as = ld4(asrc + c), ad = ld4(adst + c);
        float sa[4], sd[4];
        sa[0] = A.x * as.x + A.y * as.y + A.z * as.z + A.w * as.w;
        sa[1] = B.x * as.x + B.y * as.y + B.z * as.z + B.w * as.w;
        sa[2] = C.x * as.x + C.y * as.y + C.z * as.z + C.w * as.w;
        sa[3] = D.x * as.x + D.y * as.y + D.z * as.z + D.w * as.w;
        sd[0] = A.x * ad.x + A.y * ad.y + A.z * ad.z + A.w * ad.w;
        sd[1] = B.x * ad.x + B.y * ad.y + B.z * ad.z + B.w * ad.w;
        sd[2] = C.x * ad.x + C.y * ad.y + C.z * ad.z + C.w * ad.w;
        sd[3] = D.x * ad.x + D.y * ad.y + D.z * ad.z + D.w * ad.w;
        int gw = 32 / hh;   // lanes per head (8 or 32)
        for (int off = 1; off < gw; off <<= 1) {
#pragma unroll
            for (int j = 0; j < 4; ++j) {
                sa[j] += __shfl_xor(sa[j], off);
                sd[j] += __shfl_xor(sd[j], off);
            }
        }
        if ((cg & (gw - 1)) == 0) {
            int h = cg / gw;
            int rows[4] = {ra, rb, rc, rd};
#pragma unroll
            for (int j = 0; j < 4; ++j) {
                if (rows[j] < n) { avp[rows[j] * hh + h] = sa[j]; bvp[rows[j] * hh + h] = sd[j]; }
            }
        }
    }
}

// MLP-tail pair: two independent (X,W,b[,bn]) sets
template <int K, int M>
__global__ __launch_bounds__(256)
void tail2_k(const float* __restrict__ X0, const float* __restrict__ W0, const float* __restrict__ b0,
             const float* __restrict__ g0, const float* __restrict__ bb0, float* __restrict__ Y0,
             const float* __restrict__ X1, const float* __restrict__ W1, const float* __restrict__ b1,
             const float* __restrict__ g1, const float* __restrict__ bb1, float* __restrict__ Y1,
             int n, int gper, int do_relu) {
    constexpr int CG = M / 4, RPB = 256 / CG;
    bool s1 = blockIdx.x >= gper;
    int blk = s1 ? blockIdx.x - gper : blockIdx.x;
    const float* X = s1 ? X1 : X0;
    const float* W = s1 ? W1 : W0;
    const float* bi = s1 ? b1 : b0;
    const float* bg = s1 ? g1 : g0;
    const float* bb = s1 ? bb1 : bb0;
    float* Y = s1 ? Y1 : Y0;
    __shared__ float Ws[K * M];
    for (int i = threadIdx.x; i < K * M; i += 256) Ws[i] = W[i];
    __syncthreads();
    int cg = threadIdx.x % CG, r = threadIdx.x / CG, c = cg * 4;
    int ra = blk * (4 * RPB) + r, rb = ra + RPB, rc = ra + 2 * RPB, rd = ra + 3 * RPB;
    const float* xa = X + (size_t)(ra < n ? ra : 0) * K;
    const float* xb = X + (size_t)(rb < n ? rb : 0) * K;
    const float* xc = X + (size_t)(rc < n ? rc : 0) * K;
    const float* xd = X + (size_t)(rd < n ? rd : 0) * K;
    float4 A = f4z(), B = f4z(), C = f4z(), D = f4z();
    gemm4<K, M>(Ws, xa, xb, xc, xd, c, A, B, C, D);
    float4 bv = ld4(bi + c);
    A = f4bias(A, bv); B = f4bias(B, bv); C = f4bias(C, bv); D = f4bias(D, bv);
    if (do_relu) { A = f4relu(A); B = f4relu(B); C = f4relu(C); D = f4relu(D); }
    if (bg) {
        float4 g = ld4(bg + c);
        g = make_float4(g.x * RSQ_BN, g.y * RSQ_BN, g.z * RSQ_BN, g.w * RSQ_BN);
        float4 bbv = ld4(bb + c);
        A = f4bn(A, g, bbv); B = f4bn(B, g, bbv); C = f4bn(C, g, bbv); D = f4bn(D, g, bbv);
    }
    if (ra < n) st4(Y + (size_t)ra * M + c, A);
    if (rb < n) st4(Y + (size_t)rb * M + c, B);
    if (rc < n) st4(Y + (size_t)rc * M + c, C);
    if (rd < n) st4(Y + (size_t)rd * M + c, D);
}

// final: blend(0.6*XA+0.4*XB) @ fin -> relu -> bn -> @fin2 -> out[n,2]
__global__ __launch_bounds__(256)
void linF_k(const float* __restrict__ XA, const float* __restrict__ XB,
            const float* __restrict__ W, const float* __restrict__ bi,
            const float* __restrict__ bg, const float* __restrict__ bb,
            const float* __restrict__ w2, const float* __restrict__ b2,
            float* __restrict__ out, int n) {
    constexpr int K = 128, M = 64, CG = 16, RPB = 16;
    __shared__ float Ws[K * M];
    for (int i = threadIdx.x; i < K * M; i += 256) Ws[i] = W[i];
    __syncthreads();
    int cg = threadIdx.x % CG, r = threadIdx.x / CG, c = cg * 4;
    int ra = blockIdx.x * (4 * RPB) + r, rb = ra + RPB, rc = ra + 2 * RPB, rd = ra + 3 * RPB;
    const float* xa = XA + (size_t)(ra < n ? ra : 0) * K;
    const float* xb = XA + (size_t)(rb < n ? rb : 0) * K;
    const float* xc = XA + (size_t)(rc < n ? rc : 0) * K;
    const float* xd = XA + (size_t)(rd < n ? rd : 0) * K;
    const float* ya = XB + (size_t)(ra < n ? ra : 0) * K;
    const float* yb = XB + (size_t)(rb < n ? rb : 0) * K;
    const float* yc = XB + (size_t)(rc < n ? rc : 0) * K;
    const float* yd = XB + (size_t)(rd < n ? rd : 0) * K;
    float4 A = f4z(), B = f4z(), C = f4z(), D = f4z();
#pragma unroll 4
    for (int k = 0; k < K; k += 4) {
        float4 va = ld4(xa + k), vb = ld4(xb + k), vc = ld4(xc + k), vd = ld4(xd + k);
        float4 ua = ld4(ya + k), ub = ld4(yb + k), uc = ld4(yc + k), ud = ld4(yd + k);
        va = make_float4(0.6f * va.x + 0.4f * ua.x, 0.6f * va.y + 0.4f * ua.y,
                         0.6f * va.z + 0.4f * ua.z, 0.6f * va.w + 0.4f * ua.w);
        vb = make_float4(0.6f * vb.x + 0.4f * ub.x, 0.6f * vb.y + 0.4f * ub.y,
                         0.6f * vb.z + 0.4f * ub.z, 0.6f * vb.w + 0.4f * ub.w);
        vc = make_float4(0.6f * vc.x + 0.4f * uc.x, 0.6f * vc.y + 0.4f * uc.y,
                         0.6f * vc.z + 0.4f * uc.z, 0.6f * vc.w + 0.4f * uc.w);
        vd = make_float4(0.6f * vd.x + 0.4f * ud.x, 0.6f * vd.y + 0.4f * ud.y,
                         0.6f * vd.z + 0.4f * ud.z, 0.6f * vd.w + 0.4f * ud.w);
        const float* wp = Ws + k * M + c;
        float4 w0 = ld4(wp), w1 = ld4(wp + M), w2v = ld4(wp + 2 * M), w3 = ld4(wp + 3 * M);
        FMA4R(A, va, w0, w1, w2v, w3)
        FMA4R(B, vb, w0, w1, w2v, w3)
        FMA4R(C, vc, w0, w1, w2v, w3)
        FMA4R(D, vd, w0, w1, w2v, w3)
    }
    float4 bv = ld4(bi + c);
    A = f4relu(f4bias(A, bv)); B = f4relu(f4bias(B, bv));
    C = f4relu(f4bias(C, bv)); D = f4relu(f4bias(D, bv));
    float4 g = ld4(bg + c);
    g = make_float4(g.x * RSQ_BN, g.y * RSQ_BN, g.z * RSQ_BN, g.w * RSQ_BN);
    float4 bbv = ld4(bb + c);
    A = f4bn(A, g, bbv); B = f4bn(B, g, bbv); C = f4bn(C, g, bbv); D = f4bn(D, g, bbv);
    float w20 = w2[2 * c], w21 = w2[2 * c + 1];
    float w22 = w2[2 * c + 2], w23 = w2[2 * c + 3];
    float w24 = w2[2 * c + 4], w25 = w2[2 * c + 5];
    float w26 = w2[2 * c + 6], w27 = w2[2 * c + 7];
    float p0[4], p1[4];
    p0[0] = A.x * w20 + A.y * w22 + A.z * w24 + A.w * w26;
    p1[0] = A.x * w21 + A.y * w23 + A.z * w25 + A.w * w27;
    p0[1] = B.x * w20 + B.y * w22 + B.z * w24 + B.w * w26;
    p1[1] = B.x * w21 + B.y * w23 + B.z * w25 + B.w * w27;
    p0[2] = C.x * w20 + C.y * w22 + C.z * w24 + C.w * w26;
    p1[2] = C.x * w21 + C.y * w23 + C.z * w25 + C.w * w27;
    p0[3] = D.x * w20 + D.y * w22 + D.z * w24 + D.w * w26;
    p1[3] = D.x * w21 + D.y * w23 + D.z * w25 + D.w * w27;
    for (int off = 1; off < CG; off <<= 1) {
#pragma unroll
        for (int j = 0; j < 4; ++j) {
            p0[j] += __shfl_xor(p0[j], off);
            p1[j] += __shfl_xor(p1[j], off);
        }
    }
    if (cg == 0) {
        int rows[4] = {ra, rb, rc, rd};
#pragma unroll
        for (int j = 0; j < 4; ++j) {
            if (rows[j] < n) {
                out[rows[j] * 2] = p0[j] + b2[0];
                out[rows[j] * 2 + 1] = p1[j] + b2[1];
            }
        }
    }
}

// ---------------- merged sparse aggregation: gcn half + gat half ----------------
// 16 lanes/node, 8 cols (16B fp16) per lane; 8x unrolled edge loop.

__global__ __launch_bounds__(256)
void dual_gather_k(const int* __restrict__ rowptr, const int* __restrict__ colidx,
                   const float* __restrict__ dis,
                   const __half* __restrict__ Tg, const float* __restrict__ gbias,
                   const float* __restrict__ gbng, const float* __restrict__ gbnb,
                   const float* __restrict__ res, float* __restrict__ Yg,
                   const __half* __restrict__ Ta, const float* __restrict__ avp,
                   const float* __restrict__ bvp, const float* __restrict__ abias,
                   const float* __restrict__ abng, const float* __restrict__ abnb,
                   const float* __restrict__ fimp, float* __restrict__ Ya,
                   int n, int gper, int hh, int log2C) {
    bool gat = blockIdx.x >= gper;
    int blk = gat ? blockIdx.x - gper : blockIdx.x;
    int idx = blk * 256 + threadIdx.x;
    int i = idx >> 4;
    if (i >= n) return;
    int c = (idx & 15) * 8;
    int p0 = rowptr[i], p1 = rowptr[i + 1];
    float4 lo = f4z(), hi = f4z();

#define ACC8(qq, ww)                                                            \
    {                                                                           \
        float4 t0 = h4f(make_uint2(qq.x, qq.y)), t1 = h4f(make_uint2(qq.z, qq.w)); \
        lo.x += t0.x * ww; lo.y += t0.y * ww; lo.z += t0.z * ww; lo.w += t0.w * ww; \
        hi.x += t1.x * ww; hi.y += t1.y * ww; hi.z += t1.z * ww; hi.w += t1.w * ww; \
    }

    if (!gat) {
        int p = p0;
        for (; p + 8 <= p1; p += 8) {
            int s[8]; float w[8]; uint4 q[8];
#pragma unroll
            for (int j = 0; j < 8; ++j) s[j] = colidx[p + j];
#pragma unroll
            for (int j = 0; j < 8; ++j) w[j] = dis[s[j]];
#pragma unroll
            for (int j = 0; j < 8; ++j)
                q[j] = *reinterpret_cast<const uint4*>(Tg + (size_t)s[j] * 128 + c);
#pragma unroll
            for (int j = 0; j < 8; ++j) ACC8(q[j], w[j])
        }
        for (; p < p1; ++p) {
            int s0 = colidx[p];
            float w0 = dis[s0];
            uint4 q0 = *reinterpret_cast<const uint4*>(Tg + (size_t)s0 * 128 + c);
            ACC8(q0, w0)
        }
        float di = dis[i];
        float4 b0 = ld4(gbias + c), b1 = ld4(gbias + c + 4);
        lo = make_float4(lo.x * di + b0.x, lo.y * di + b0.y, lo.z * di + b0.z, lo.w * di + b0.w);
        hi = make_float4(hi.x * di + b1.x, hi.y * di + b1.y, hi.z * di + b1.z, hi.w * di + b1.w);
        float4 g0 = ld4(gbng + c), g1 = ld4(gbng + c + 4);
        g0 = make_float4(g0.x * RSQ_BN, g0.y * RSQ_BN, g0.z * RSQ_BN, g0.w * RSQ_BN);
        g1 = make_float4(g1.x * RSQ_BN, g1.y * RSQ_BN, g1.z * RSQ_BN, g1.w * RSQ_BN);
        float4 h0 = ld4(gbnb + c), h1 = ld4(gbnb + c + 4);
        lo = f4relu(f4bn(lo, g0, h0));
        hi = f4relu(f4bn(hi, g1, h1));
        if (res) {
            float4 r0 = ld4(res + (size_t)i * 128 + c), r1 = ld4(res + (size_t)i * 128 + c + 4);
            lo = f4bias(lo, r0); hi = f4bias(hi, r1);
        }
        st4(Yg + (size_t)i * 128 + c, lo);
        st4(Yg + (size_t)i * 128 + c + 4, hi);
    } else {
        int h = c >> log2C;
        float ad = bvp[i * hh + h];
        float m = -3.0e38f, s = 0.f;
        int p = p0;
        for (; p + 8 <= p1; p += 8) {
            int sx[8]; float e[8]; uint4 q[8];
#pragma unroll
            for (int j = 0; j < 8; ++j) sx[j] = colidx[p + j];
#pragma unroll
            for (int j = 0; j < 8; ++j) e[j] = leaky02(avp[sx[j] * hh + h] + ad);
#pragma unroll
            for (int j = 0; j < 8; ++j)
                q[j] = *reinterpret_cast<const uint4*>(Ta + (size_t)sx[j] * 128 + c);
            float mc = fmaxf(fmaxf(fmaxf(e[0], e[1]), fmaxf(e[2], e[3])),
                             fmaxf(fmaxf(e[4], e[5]), fmaxf(e[6], e[7])));
            float mn = fmaxf(m, mc);
            float scale = expf(m - mn);
            float wsum = 0.f;
            lo = make_float4(lo.x * scale, lo.y * scale, lo.z * scale, lo.w * scale);
            hi = make_float4(hi.x * scale, hi.y * scale, hi.z * scale, hi.w * scale);
#pragma unroll
            for (int j = 0; j < 8; ++j) {
                float wj = expf(e[j] - mn);
                wsum += wj;
                ACC8(q[j], wj)
            }
            s = s * scale + wsum;
            m = mn;
        }
        for (; p < p1; ++p) {
            int s0 = colidx[p];
            float e0 = leaky02(avp[s0 * hh + h] + ad);
            float mn = fmaxf(m, e0);
            float scale = expf(m - mn);
            float w0 = expf(e0 - mn);
            s = s * scale + w0;
            lo = make_float4(lo.x * scale, lo.y * scale, lo.z * scale, lo.w * scale);
            hi = make_float4(hi.x * scale, hi.y * scale, hi.z * scale, hi.w * scale);
            uint4 q0 = *reinterpret_cast<const uint4*>(Ta + (size_t)s0 * 128 + c);
            ACC8(q0, w0)
            m = mn;
        }
        float si = 1.f / (s + 1e-16f);
        float4 b0 = ld4(abias + c), b1 = ld4(abias + c + 4);
        lo = make_float4(lo.x * si + b0.x, lo.y * si + b0.y, lo.z * si + b0.z, lo.w * si + b0.w);
        hi = make_float4(hi.x * si + b1.x, hi.y * si + b1.y, hi.z * si + b1.z, hi.w * si + b1.w);
        float4 g0 = ld4(abng + c), g1 = ld4(abng + c + 4);
        g0 = make_float4(g0.x * RSQ_BN, g0.y * RSQ_BN, g0.z * RSQ_BN, g0.w * RSQ_BN);
        g1 = make_float4(g1.x * RSQ_BN, g1.y * RSQ_BN, g1.z * RSQ_BN, g1.w * RSQ_BN);
        float4 h0 = ld4(abnb + c), h1 = ld4(abnb + c + 4);
        lo = f4bn(lo, g0, h0);
        hi = f4bn(hi, g1, h1);
        lo.x = lo.x > 0.f ? lo.x : expm1f(lo.x);
        lo.y = lo.y > 0.f ? lo.y : expm1f(lo.y);
        lo.z = lo.z > 0.f ? lo.z : expm1f(lo.z);
        lo.w = lo.w > 0.f ? lo.w : expm1f(lo.w);
        hi.x = hi.x > 0.f ? hi.x : expm1f(hi.x);
        hi.y = hi.y > 0.f ? hi.y : expm1f(hi.y);
        hi.z = hi.z > 0.f ? hi.z : expm1f(hi.z);
        hi.w = hi.w > 0.f ? hi.w : expm1f(hi.w);
        if (fimp) {
            float4 f0 = ld4(fimp + c), f1 = ld4(fimp + c + 4);
            lo = make_float4(lo.x * f0.x, lo.y * f0.y, lo.z * f0.z, lo.w * f0.w);
            hi = make_float4(hi.x * f1.x, hi.y * f1.y, hi.z * f1.z, hi.w * f1.w);
        }
        st4(Ya + (size_t)i * 128 + c, lo);
        st4(Ya + (size_t)i * 128 + c + 4, hi);
    }
#undef ACC8
}

// ---------------- host orchestration ----------------

static inline int cdiv(int a, int b) { return (a + b - 1) / b; }

extern "C" void kernel_launch(void* const* d_in, const int* in_sizes, int n_in,
                              void* d_out, int out_size, void* d_ws, size_t ws_size,
                              hipStream_t stream) {
    const float* x       = (const float*)d_in[0];
    const int*   ei      = (const int*)d_in[1];
    const float* gcn_in_w = (const float*)d_in[2];
    const float* gcn_in_b = (const float*)d_in[3];
    const float* gcn_res_w = (const float*)d_in[4];
    const float* gcn_res_b = (const float*)d_in[5];
    const float* gcn_w   = (const float*)d_in[6];
    const float* gcn_b   = (const float*)d_in[7];
    const float* gcn_bn_g = (const float*)d_in[8];
    const float* gcn_bn_b = (const float*)d_in[9];
    const float* gcn_c1w = (const float*)d_in[10];
    const float* gcn_c1b = (const float*)d_in[11];
    const float* gcn_c2w = (const float*)d_in[12];
    const float* gcn_c2b = (const float*)d_in[13];
    const float* gcn_c3w = (const float*)d_in[14];
    const float* gcn_c3b = (const float*)d_in[15];
    const float* gat_in_w = (const float*)d_in[16];
    const float* gat_in_b = (const float*)d_in[17];
    const float* gat_w   = (const float*)d_in[18];
    const float* gat_asrc = (const float*)d_in[19];
    const float* gat_adst = (const float*)d_in[20];
    const float* gat_b   = (const float*)d_in[21];
    const float* gat_bn_g = (const float*)d_in[22];
    const float* gat_bn_b = (const float*)d_in[23];
    const float* feat_imp = (const float*)d_in[24];
    const float* gat_c1w = (const float*)d_in[25];
    const float* gat_c1b = (const float*)d_in[26];
    const float* gat_cbn_g = (const float*)d_in[27];
    const float* gat_cbn_b = (const float*)d_in[28];
    const float* gat_c2w = (const float*)d_in[29];
    const float* gat_c2b = (const float*)d_in[30];
    const float* gat_c3w = (const float*)d_in[31];
    const float* gat_c3b = (const float*)d_in[32];
    const float* fin_w   = (const float*)d_in[33];
    const float* fin_b   = (const float*)d_in[34];
    const float* fin_bn_g = (const float*)d_in[35];
    const float* fin_bn_b = (const float*)d_in[36];
    const float* fin2_w  = (const float*)d_in[37];
    const float* fin2_b  = (const float*)d_in[38];

    const int N = in_sizes[0] / 64;
    const int E = in_sizes[1] / 2;
    const int EN = E + N;
    const int* esrc = ei;
    const int* edst = ei + E;

    // workspace carve (256B aligned)
    char* wp = (char*)d_ws;
    auto alloc = [&](size_t bytes) -> void* {
        void* p = (void*)wp;
        wp += (bytes + 255) & ~(size_t)255;
        return p;
    };
    int* cnt    = (int*)alloc((size_t)N * 4);
    int* rowptr = (int*)alloc((size_t)(N + 1) * 4);
    int* cursor = (int*)alloc((size_t)N * 4);
    int* bsum   = (int*)alloc((size_t)256 * 4);
    int* colidx = (int*)alloc((size_t)EN * 4);
    float* dis  = (float*)alloc((size_t)N * 4);
    float* A    = (float*)alloc((size_t)N * 128 * 4);   // gcn ping / GOUT reuse
    float* B    = (float*)alloc((size_t)N * 128 * 4);   // gcn pong
    float* G    = (float*)alloc((size_t)N * 128 * 4);   // gat ping / AOUT reuse
    float* H    = (float*)alloc((size_t)N * 128 * 4);   // gat pong
    float* R    = (float*)alloc((size_t)N * 128 * 4);   // gcn residual
    __half* Th1 = (__half*)alloc((size_t)N * 128 * 2);  // aliased as h1g after layers
    __half* Th2 = (__half*)alloc((size_t)N * 128 * 2);  // aliased as h1a after layers
    float* h2g  = (float*)alloc((size_t)N * 32 * 4);
    float* h2a  = (float*)alloc((size_t)N * 32 * 4);
    float* avv  = (float*)alloc((size_t)N * 4 * 4);
    float* bvv  = (float*)alloc((size_t)N * 4 * 4);
    float* h1g = (float*)Th1;   // N*64*4 == N*128*2 bytes
    float* h1a = (float*)Th2;

    // ---- CSR build ----
    const int nScanB = cdiv(N, 256);
    zero_i32_k<<<cdiv(N, 256), 256, 0, stream>>>(cnt, N);
    hist_k<<<cdiv(EN, 256), 256, 0, stream>>>(edst, cnt, E, EN);
    scanA_k<<<nScanB, 256, 0, stream>>>(cnt, rowptr, bsum, N);
    scanB_k<<<1, 256, 0, stream>>>(bsum, nScanB);
    scanC_k<<<nScanB, 256, 0, stream>>>(cnt, bsum, rowptr, cursor, dis, N, EN);
    scatter_k<<<cdiv(EN, 256), 256, 0, stream>>>(esrc, edst, cursor, colidx, E, EN);

    const int g32r  = cdiv(N, 32);    // M=128, 4-row blocks (32 rows/block)
    const int g64r  = cdiv(N, 64);    // M=64
    const int g128r = cdiv(N, 128);   // M=32
    const int gG    = cdiv(N, 16);    // gather: 16 nodes/block

    // ---- input stage: gcn_in -> A, gcn_res -> R, gat_in -> G ----
    lin3_k<<<3 * g32r, 256, 0, stream>>>(x, gcn_in_w, gcn_in_b, A,
                                         gcn_res_w, gcn_res_b, R,
                                         gat_in_w, gat_in_b, G, N, g32r);

    // ---- 3 layers, both branches in lockstep ----
    const int heads_arr[3] = {4, 4, 1};
    float* gcur = A; float* gnxt = B;
    float* acur = G; float* anxt = H;
    for (int i = 0; i < 3; ++i) {
        int hh = heads_arr[i];
        int log2C = (hh == 4) ? 5 : 7;
        dual128_k<<<2 * g32r, 256, 0, stream>>>(gcur, gcn_w + (size_t)i * 16384, Th1,
                                                acur, gat_w + (size_t)i * 16384, Th2,
                                                gat_asrc + i * 128, gat_adst + i * 128,
                                                avv, bvv, hh, N, g32r);
        dual_gather_k<<<2 * gG, 256, 0, stream>>>(rowptr, colidx, dis,
                                                  Th1, gcn_b + i * 128, gcn_bn_g + i * 128,
                                                  gcn_bn_b + i * 128, (i == 1) ? R : nullptr, gnxt,
                                                  Th2, avv, bvv, gat_b + i * 128,
                                                  gat_bn_g + i * 128, gat_bn_b + i * 128,
                                                  (i == 2) ? feat_imp : nullptr, anxt,
                                                  N, gG, hh, log2C);
        float* t = gcur; gcur = gnxt; gnxt = t;
        t = acur; acur = anxt; anxt = t;
    }
    // gcur = gcn final xp (B), acur = gat final xg (H)

    // ---- MLP tails (pairs) ----  (h1g/h1a alias Th1/Th2 — Th no longer needed)
    tail2_k<128, 64><<<2 * g64r, 256, 0, stream>>>(
        gcur, gcn_c1w, gcn_c1b, nullptr, nullptr, h1g,
        acur, gat_c1w, gat_c1b, gat_cbn_g, gat_cbn_b, h1a, N, g64r, 1);
    tail2_k<64, 32><<<2 * g128r, 256, 0, stream>>>(
        h1g, gcn_c2w, gcn_c2b, nullptr, nullptr, h2g,
        h1a, gat_c2w, gat_c2b, nullptr, nullptr, h2a, N, g128r, 1);
    tail2_k<32, 128><<<2 * g32r, 256, 0, stream>>>(
        h2g, gcn_c3w, gcn_c3b, nullptr, nullptr, A,
        h2a, gat_c3w, gat_c3b, nullptr, nullptr, G, N, g32r, 0);

    // ---- fusion tail: blend + fin linear + bn + classifier ----
    linF_k<<<g64r, 256, 0, stream>>>(A, G, fin_w, fin_b, fin_bn_g, fin_bn_b,
                                     fin2_w, fin2_b, (float*)d_out, N);
}